// Round 9
// baseline (3288.455 us; speedup 1.0000x reference)
//
#include <hip/hip_runtime.h>
#include <hip/hip_bf16.h>

#define IN_F   128
#define EF     32
#define OUT_F  128

// ---------------------------------------------------------------------------
// Phase 2: edge scatter. Half-wave (32 lanes) per edge.
//   sum_src accumulates INTO d_out (zeroed first) to avoid needing 51 MB of
//   workspace (round-2 post-mortem: ws overflow corrupted pristine inputs).
// ---------------------------------------------------------------------------
__global__ __launch_bounds__(256) void edge_agg(
    const float* __restrict__ feat, const float* __restrict__ ef,
    const int* __restrict__ src, const int* __restrict__ dst,
    float* sum_src /* = d_out */, float* __restrict__ sum_edge,
    float* __restrict__ deg, int E)
{
    const int gid  = blockIdx.x * blockDim.x + threadIdx.x;
    const int wave = gid >> 6;
    const int lane = threadIdx.x & 63;
    const int sub  = lane >> 5;      // which edge of the pair
    const int l    = lane & 31;      // lane within half-wave
    const int nw   = (gridDim.x * blockDim.x) >> 6;

    for (int e2 = wave * 2; e2 < E; e2 += nw * 2) {
        const int e = e2 + sub;
        if (e < E) {
            const int s = src[e];
            const int d = dst[e];
            const float4 v = *reinterpret_cast<const float4*>(
                feat + (size_t)s * IN_F + l * 4);
            float* row = sum_src + (size_t)d * IN_F + l * 4;
            unsafeAtomicAdd(row + 0, v.x);
            unsafeAtomicAdd(row + 1, v.y);
            unsafeAtomicAdd(row + 2, v.z);
            unsafeAtomicAdd(row + 3, v.w);
            const float ev = ef[(size_t)e * EF + l];
            unsafeAtomicAdd(sum_edge + (size_t)d * EF + l, ev);
            if (l == 0) unsafeAtomicAdd(deg + d, 1.0f);
        }
    }
}

// ---------------------------------------------------------------------------
// Phase 3: out = [feat ; sum_src/den ; sum_edge/den] @ [W_self ; W_neigh] + b
// sum_src aliases out: all reads of out-rows (own block only) happen before
// the final __syncthreads(); the epilogue write comes after. Race-free.
// ---------------------------------------------------------------------------
__global__ __launch_bounds__(256) void node_gemm(
    const float* __restrict__ feat, const float* sum_src,
    const float* __restrict__ sum_edge, const float* __restrict__ deg,
    const float* __restrict__ W_self, const float* __restrict__ W_neigh,
    const float* __restrict__ bias, float* out, int N)
{
    __shared__ float xs[32][32];    // [node][k]
    __shared__ float ws[32][128];   // [k][out]
    __shared__ float inv[32];
    __shared__ float bs[128];

    const int t    = threadIdx.x;
    const int tcol = t & 31;        // outputs tcol*4 .. +3
    const int trow = t >> 5;        // nodes trow*4 .. +3
    const int base = blockIdx.x * 32;

    if (t < 128) bs[t] = bias[t];
    if (t < 32) {
        const int nv = base + t;
        const float d = (nv < N) ? deg[nv] : 1.0f;
        inv[t] = 1.0f / fmaxf(d, 1.0f);
    }
    __syncthreads();

    float acc[4][4];
#pragma unroll
    for (int i = 0; i < 4; ++i)
#pragma unroll
        for (int j = 0; j < 4; ++j) acc[i][j] = 0.0f;

    // staging coordinates
    const int snode = t >> 3;         // 0..31
    const int skk   = (t & 7) * 4;    // 0,4,..,28

#pragma unroll 1
    for (int kc = 0; kc < 9; ++kc) {
        const int k0 = kc * 32;

        // ---- stage x tile (32 nodes x 32 k) ----
        {
            const int nv = base + snode;
            float4 v = make_float4(0.f, 0.f, 0.f, 0.f);
            if (nv < N) {
                if (kc < 4) {
                    v = *reinterpret_cast<const float4*>(
                        feat + (size_t)nv * IN_F + k0 + skk);
                } else if (kc < 8) {
                    v = *reinterpret_cast<const float4*>(
                        sum_src + (size_t)nv * IN_F + (k0 - 128) + skk);
                    const float s = inv[snode];
                    v.x *= s; v.y *= s; v.z *= s; v.w *= s;
                } else {
                    v = *reinterpret_cast<const float4*>(
                        sum_edge + (size_t)nv * EF + skk);
                    const float s = inv[snode];
                    v.x *= s; v.y *= s; v.z *= s; v.w *= s;
                }
            }
            *reinterpret_cast<float4*>(&xs[snode][skk]) = v;
        }

        // ---- stage W tile (32 k x 128 out) ----
#pragma unroll
        for (int p = 0; p < 4; ++p) {
            const int ei  = p * 1024 + t * 4;
            const int row = ei >> 7;
            const int col = ei & 127;
            float4 w4;
            if (kc < 4) {
                w4 = *reinterpret_cast<const float4*>(
                    W_self + (size_t)(k0 + row) * OUT_F + col);
            } else {
                w4 = *reinterpret_cast<const float4*>(
                    W_neigh + (size_t)(k0 - 128 + row) * OUT_F + col);
            }
            *reinterpret_cast<float4*>(&ws[row][col]) = w4;
        }
        __syncthreads();

        // ---- compute ----
#pragma unroll
        for (int kk = 0; kk < 32; ++kk) {
            const float4 b = *reinterpret_cast<const float4*>(&ws[kk][tcol * 4]);
#pragma unroll
            for (int i = 0; i < 4; ++i) {
                const float a = xs[trow * 4 + i][kk];
                acc[i][0] = fmaf(a, b.x, acc[i][0]);
                acc[i][1] = fmaf(a, b.y, acc[i][1]);
                acc[i][2] = fmaf(a, b.z, acc[i][2]);
                acc[i][3] = fmaf(a, b.w, acc[i][3]);
            }
        }
        __syncthreads();
    }

    // ---- epilogue (after final barrier: all out-reads are done) ----
#pragma unroll
    for (int i = 0; i < 4; ++i) {
        const int nv = base + trow * 4 + i;
        if (nv < N) {
            float4 r;
            r.x = acc[i][0] + bs[tcol * 4 + 0];
            r.y = acc[i][1] + bs[tcol * 4 + 1];
            r.z = acc[i][2] + bs[tcol * 4 + 2];
            r.w = acc[i][3] + bs[tcol * 4 + 3];
            *reinterpret_cast<float4*>(out + (size_t)nv * OUT_F + tcol * 4) = r;
        }
    }
}

extern "C" void kernel_launch(void* const* d_in, const int* in_sizes, int n_in,
                              void* d_out, int out_size, void* d_ws, size_t ws_size,
                              hipStream_t stream) {
    const float* feat    = (const float*)d_in[0];
    const float* efeats  = (const float*)d_in[1];
    const int*   src     = (const int*)d_in[2];
    const int*   dst     = (const int*)d_in[3];
    const float* W_self  = (const float*)d_in[4];
    const float* W_neigh = (const float*)d_in[5];
    const float* bias    = (const float*)d_in[6];
    float* out = (float*)d_out;

    const int N = in_sizes[0] / IN_F;   // 100000
    const int E = in_sizes[2];          // 1600000

    // Workspace: ONLY sum_edge [N,32] + deg [N]  (13.2 MB total)
    float* sum_edge = (float*)d_ws;
    float* deg      = sum_edge + (size_t)N * EF;
    const size_t ws_bytes = ((size_t)N * EF + N) * sizeof(float);

    // d_out doubles as the sum_src accumulator [N,128]
    hipMemsetAsync(d_out, 0, (size_t)N * IN_F * sizeof(float), stream);
    hipMemsetAsync(d_ws, 0, ws_bytes, stream);

    edge_agg<<<4096, 256, 0, stream>>>(feat, efeats, src, dst,
                                       out, sum_edge, deg, E);

    const int nblk = (N + 31) / 32;
    node_gemm<<<nblk, 256, 0, stream>>>(feat, out, sum_edge, deg,
                                        W_self, W_neigh, bias, out, N);
}

// Round 11
// 925.477 us; speedup vs baseline: 3.5533x; 3.5533x over previous
//
#include <hip/hip_runtime.h>
#include <hip/hip_bf16.h>

#define IN_F   128
#define EF     32
#define OUT_F  128
#define SCAN_BLK 2048   // elements per scan block (256 thr x 8)

// ===========================================================================
// CSR-path kernels (scatter -> gather; no float atomics)
// ===========================================================================
__global__ __launch_bounds__(256) void hist_kernel(
    const int* __restrict__ dst, int* __restrict__ deg, int E)
{
    int i = blockIdx.x * blockDim.x + threadIdx.x;
    const int stride = gridDim.x * blockDim.x;
    for (; i < E; i += stride) atomicAdd(&deg[dst[i]], 1);
}

__global__ __launch_bounds__(256) void scanA(
    const int* __restrict__ deg, int* __restrict__ partial, int N)
{
    __shared__ int sdata[256];
    const int base = blockIdx.x * SCAN_BLK;
    int s = 0;
#pragma unroll
    for (int j = 0; j < 8; ++j) {
        const int idx = base + threadIdx.x * 8 + j;
        if (idx < N) s += deg[idx];
    }
    sdata[threadIdx.x] = s;
    __syncthreads();
    for (int off = 128; off > 0; off >>= 1) {
        if (threadIdx.x < (unsigned)off) sdata[threadIdx.x] += sdata[threadIdx.x + off];
        __syncthreads();
    }
    if (threadIdx.x == 0) partial[blockIdx.x] = sdata[0];
}

__global__ __launch_bounds__(64) void scanB(int* partial, int NB)
{
    __shared__ int s[64];
    if ((int)threadIdx.x < NB) s[threadIdx.x] = partial[threadIdx.x];
    __syncthreads();
    if (threadIdx.x == 0) {
        int run = 0;
        for (int i = 0; i < NB; ++i) { const int v = s[i]; s[i] = run; run += v; }
    }
    __syncthreads();
    if ((int)threadIdx.x < NB) partial[threadIdx.x] = s[threadIdx.x];
}

__global__ __launch_bounds__(256) void scanC(
    const int* __restrict__ deg, const int* __restrict__ partial,
    int* __restrict__ row_start, int* __restrict__ cursor, int N)
{
    __shared__ int ssum[256];
    const int base = blockIdx.x * SCAN_BLK;
    int loc[8];
    int s = 0;
#pragma unroll
    for (int j = 0; j < 8; ++j) {
        const int idx = base + threadIdx.x * 8 + j;
        loc[j] = (idx < N) ? deg[idx] : 0;
        s += loc[j];
    }
    ssum[threadIdx.x] = s;
    __syncthreads();
    // inclusive Hillis-Steele scan over 256 thread sums
    for (int off = 1; off < 256; off <<= 1) {
        const int mine = ssum[threadIdx.x];
        const int add  = (threadIdx.x >= (unsigned)off) ? ssum[threadIdx.x - off] : 0;
        __syncthreads();
        ssum[threadIdx.x] = mine + add;
        __syncthreads();
    }
    int run = partial[blockIdx.x] + ssum[threadIdx.x] - s;  // exclusive offset
#pragma unroll
    for (int j = 0; j < 8; ++j) {
        const int idx = base + threadIdx.x * 8 + j;
        if (idx < N) { row_start[idx] = run; cursor[idx] = run; run += loc[j]; }
    }
}

__global__ __launch_bounds__(256) void fill_kernel(
    const int* __restrict__ src, const int* __restrict__ dst,
    int* __restrict__ cursor, int2* __restrict__ csr, int E)
{
    int i = blockIdx.x * blockDim.x + threadIdx.x;
    const int stride = gridDim.x * blockDim.x;
    for (; i < E; i += stride) {
        const int d = dst[i];
        const int pos = atomicAdd(&cursor[d], 1);
        csr[pos] = make_int2(src[i], i);
    }
}

// One wave per node: accumulate in-edges in registers, write mean ONCE.
__global__ __launch_bounds__(256) void gather_kernel(
    const float* __restrict__ feat, const float* __restrict__ ef,
    const int2* __restrict__ csr, const int* __restrict__ row_start,
    const int* __restrict__ deg,
    float* __restrict__ mean_src /* = d_out */, float* __restrict__ mean_edge,
    int N)
{
    const int v = blockIdx.x * 4 + (threadIdx.x >> 6);
    const int lane = threadIdx.x & 63;
    if (v >= N) return;
    const int start = row_start[v];
    const int dv    = deg[v];
    float2 acc = make_float2(0.f, 0.f);
    float accE = 0.f;
    for (int i = 0; i < dv; ++i) {
        const int2 p = csr[start + i];
        const float2 f2 = *reinterpret_cast<const float2*>(
            feat + (size_t)p.x * IN_F + lane * 2);
        acc.x += f2.x; acc.y += f2.y;
        if (lane < EF) accE += ef[(size_t)p.y * EF + lane];
    }
    const float s = 1.0f / fmaxf((float)dv, 1.0f);
    float2 r; r.x = acc.x * s; r.y = acc.y * s;
    *reinterpret_cast<float2*>(mean_src + (size_t)v * IN_F + lane * 2) = r;
    if (lane < EF) mean_edge[(size_t)v * EF + lane] = accE * s;
}

// ===========================================================================
// Fallback-path kernel (proven round-9 atomic scatter), used if ws too small
// ===========================================================================
__global__ __launch_bounds__(256) void edge_agg(
    const float* __restrict__ feat, const float* __restrict__ ef,
    const int* __restrict__ src, const int* __restrict__ dst,
    float* sum_src /* = d_out */, float* __restrict__ sum_edge,
    float* __restrict__ deg, int E)
{
    const int gid  = blockIdx.x * blockDim.x + threadIdx.x;
    const int wave = gid >> 6;
    const int lane = threadIdx.x & 63;
    const int sub  = lane >> 5;
    const int l    = lane & 31;
    const int nw   = (gridDim.x * blockDim.x) >> 6;

    for (int e2 = wave * 2; e2 < E; e2 += nw * 2) {
        const int e = e2 + sub;
        if (e < E) {
            const int s = src[e];
            const int d = dst[e];
            const float4 v = *reinterpret_cast<const float4*>(
                feat + (size_t)s * IN_F + l * 4);
            float* row = sum_src + (size_t)d * IN_F + l * 4;
            unsafeAtomicAdd(row + 0, v.x);
            unsafeAtomicAdd(row + 1, v.y);
            unsafeAtomicAdd(row + 2, v.z);
            unsafeAtomicAdd(row + 3, v.w);
            const float ev = ef[(size_t)e * EF + l];
            unsafeAtomicAdd(sum_edge + (size_t)d * EF + l, ev);
            if (l == 0) unsafeAtomicAdd(deg + d, 1.0f);
        }
    }
}

// ===========================================================================
// Node GEMM: out = [feat ; nsrc*inv ; nedge*inv] @ [W_self ; W_neigh] + bias
// need_inv=0 -> inputs are already means (CSR path). sum_src aliases out:
// own-block rows read before final barrier, written after. Race-free.
// ===========================================================================
__global__ __launch_bounds__(256) void node_gemm(
    const float* __restrict__ feat, const float* sum_src,
    const float* __restrict__ sum_edge, const float* __restrict__ deg,
    const float* __restrict__ W_self, const float* __restrict__ W_neigh,
    const float* __restrict__ bias, float* out, int N, int need_inv)
{
    __shared__ float xs[32][32];    // [node][k]
    __shared__ float ws[32][128];   // [k][out]
    __shared__ float inv[32];
    __shared__ float bs[128];

    const int t    = threadIdx.x;
    const int tcol = t & 31;
    const int trow = t >> 5;
    const int base = blockIdx.x * 32;

    if (t < 128) bs[t] = bias[t];
    if (t < 32) {
        float iv = 1.0f;
        if (need_inv) {
            const int nv = base + t;
            const float d = (nv < N) ? deg[nv] : 1.0f;
            iv = 1.0f / fmaxf(d, 1.0f);
        }
        inv[t] = iv;
    }
    __syncthreads();

    float acc[4][4];
#pragma unroll
    for (int i = 0; i < 4; ++i)
#pragma unroll
        for (int j = 0; j < 4; ++j) acc[i][j] = 0.0f;

    const int snode = t >> 3;
    const int skk   = (t & 7) * 4;

#pragma unroll 1
    for (int kc = 0; kc < 9; ++kc) {
        const int k0 = kc * 32;

        {
            const int nv = base + snode;
            float4 v = make_float4(0.f, 0.f, 0.f, 0.f);
            if (nv < N) {
                if (kc < 4) {
                    v = *reinterpret_cast<const float4*>(
                        feat + (size_t)nv * IN_F + k0 + skk);
                } else if (kc < 8) {
                    v = *reinterpret_cast<const float4*>(
                        sum_src + (size_t)nv * IN_F + (k0 - 128) + skk);
                    const float s = inv[snode];
                    v.x *= s; v.y *= s; v.z *= s; v.w *= s;
                } else {
                    v = *reinterpret_cast<const float4*>(
                        sum_edge + (size_t)nv * EF + skk);
                    const float s = inv[snode];
                    v.x *= s; v.y *= s; v.z *= s; v.w *= s;
                }
            }
            *reinterpret_cast<float4*>(&xs[snode][skk]) = v;
        }

#pragma unroll
        for (int p = 0; p < 4; ++p) {
            const int ei  = p * 1024 + t * 4;
            const int row = ei >> 7;
            const int col = ei & 127;
            float4 w4;
            if (kc < 4) {
                w4 = *reinterpret_cast<const float4*>(
                    W_self + (size_t)(k0 + row) * OUT_F + col);
            } else {
                w4 = *reinterpret_cast<const float4*>(
                    W_neigh + (size_t)(k0 - 128 + row) * OUT_F + col);
            }
            *reinterpret_cast<float4*>(&ws[row][col]) = w4;
        }
        __syncthreads();

#pragma unroll
        for (int kk = 0; kk < 32; ++kk) {
            const float4 b = *reinterpret_cast<const float4*>(&ws[kk][tcol * 4]);
#pragma unroll
            for (int i = 0; i < 4; ++i) {
                const float a = xs[trow * 4 + i][kk];
                acc[i][0] = fmaf(a, b.x, acc[i][0]);
                acc[i][1] = fmaf(a, b.y, acc[i][1]);
                acc[i][2] = fmaf(a, b.z, acc[i][2]);
                acc[i][3] = fmaf(a, b.w, acc[i][3]);
            }
        }
        __syncthreads();
    }

#pragma unroll
    for (int i = 0; i < 4; ++i) {
        const int nv = base + trow * 4 + i;
        if (nv < N) {
            float4 r;
            r.x = acc[i][0] + bs[tcol * 4 + 0];
            r.y = acc[i][1] + bs[tcol * 4 + 1];
            r.z = acc[i][2] + bs[tcol * 4 + 2];
            r.w = acc[i][3] + bs[tcol * 4 + 3];
            *reinterpret_cast<float4*>(out + (size_t)nv * OUT_F + tcol * 4) = r;
        }
    }
}

extern "C" void kernel_launch(void* const* d_in, const int* in_sizes, int n_in,
                              void* d_out, int out_size, void* d_ws, size_t ws_size,
                              hipStream_t stream) {
    const float* feat    = (const float*)d_in[0];
    const float* efeats  = (const float*)d_in[1];
    const int*   src     = (const int*)d_in[2];
    const int*   dst     = (const int*)d_in[3];
    const float* W_self  = (const float*)d_in[4];
    const float* W_neigh = (const float*)d_in[5];
    const float* bias    = (const float*)d_in[6];
    float* out = (float*)d_out;

    const int N = in_sizes[0] / IN_F;   // 100000
    const int E = in_sizes[2];          // 1600000
    const int nblk_gemm = (N + 31) / 32;

    // ---- CSR-path workspace layout ----
    // [mean_edge: N*EF f32][csr: E int2][deg:int N][row_start:int N]
    // [cursor:int N][partial:int 64]
    char* p = (char*)d_ws;
    float* mean_edge = (float*)p;                 p += (size_t)N * EF * sizeof(float);
    int2*  csr       = (int2*)p;                  p += (size_t)E * sizeof(int2);
    int*   deg_i     = (int*)p;                   p += (size_t)N * sizeof(int);
    int*   row_start = (int*)p;                   p += (size_t)N * sizeof(int);
    int*   cursor    = (int*)p;                   p += (size_t)N * sizeof(int);
    int*   partial   = (int*)p;                   p += 64 * sizeof(int);
    const size_t need_csr = (size_t)(p - (char*)d_ws);

    if (ws_size >= need_csr) {
        // ======== CSR path: build bins, then atomic-free gather ========
        const int NB = (N + SCAN_BLK - 1) / SCAN_BLK;   // 49 <= 64
        hipMemsetAsync(deg_i, 0, (size_t)N * sizeof(int), stream);
        hist_kernel<<<1024, 256, 0, stream>>>(dst, deg_i, E);
        scanA<<<NB, 256, 0, stream>>>(deg_i, partial, N);
        scanB<<<1, 64, 0, stream>>>(partial, NB);
        scanC<<<NB, 256, 0, stream>>>(deg_i, partial, row_start, cursor, N);
        fill_kernel<<<1024, 256, 0, stream>>>(src, dst, cursor, csr, E);
        gather_kernel<<<(N + 3) / 4, 256, 0, stream>>>(
            feat, efeats, csr, row_start, deg_i, out, mean_edge, N);
        node_gemm<<<nblk_gemm, 256, 0, stream>>>(
            feat, out, mean_edge, (const float*)deg_i /*unused*/,
            W_self, W_neigh, bias, out, N, /*need_inv=*/0);
    } else {
        // ======== Fallback: proven round-9 atomic-scatter path ========
        float* sum_edge = (float*)d_ws;
        float* deg_f    = sum_edge + (size_t)N * EF;
        const size_t ws_bytes = ((size_t)N * EF + N) * sizeof(float);
        hipMemsetAsync(d_out, 0, (size_t)N * IN_F * sizeof(float), stream);
        hipMemsetAsync(d_ws, 0, ws_bytes, stream);
        edge_agg<<<4096, 256, 0, stream>>>(feat, efeats, src, dst,
                                           out, sum_edge, deg_f, E);
        node_gemm<<<nblk_gemm, 256, 0, stream>>>(
            feat, out, sum_edge, deg_f,
            W_self, W_neigh, bias, out, N, /*need_inv=*/1);
    }
}

// Round 15
// 761.049 us; speedup vs baseline: 4.3209x; 1.2161x over previous
//
#include <hip/hip_runtime.h>
#include <hip/hip_bf16.h>

#define IN_F   128
#define EF     32
#define OUT_F  128
#define SCAN_BLK 2048   // elements per scan block (256 thr x 8)

// ===========================================================================
// CSR-path kernels (scatter -> gather; no float atomics)
// ===========================================================================
__global__ __launch_bounds__(256) void hist_kernel(
    const int* __restrict__ dst, int* __restrict__ deg, int E)
{
    int i = blockIdx.x * blockDim.x + threadIdx.x;
    const int stride = gridDim.x * blockDim.x;
    for (; i < E; i += stride) atomicAdd(&deg[dst[i]], 1);
}

__global__ __launch_bounds__(256) void scanA(
    const int* __restrict__ deg, int* __restrict__ partial, int N)
{
    __shared__ int sdata[256];
    const int base = blockIdx.x * SCAN_BLK;
    int s = 0;
#pragma unroll
    for (int j = 0; j < 8; ++j) {
        const int idx = base + threadIdx.x * 8 + j;
        if (idx < N) s += deg[idx];
    }
    sdata[threadIdx.x] = s;
    __syncthreads();
    for (int off = 128; off > 0; off >>= 1) {
        if (threadIdx.x < (unsigned)off) sdata[threadIdx.x] += sdata[threadIdx.x + off];
        __syncthreads();
    }
    if (threadIdx.x == 0) partial[blockIdx.x] = sdata[0];
}

__global__ __launch_bounds__(64) void scanB(int* partial, int NB)
{
    __shared__ int s[64];
    if ((int)threadIdx.x < NB) s[threadIdx.x] = partial[threadIdx.x];
    __syncthreads();
    if (threadIdx.x == 0) {
        int run = 0;
        for (int i = 0; i < NB; ++i) { const int v = s[i]; s[i] = run; run += v; }
    }
    __syncthreads();
    if ((int)threadIdx.x < NB) partial[threadIdx.x] = s[threadIdx.x];
}

__global__ __launch_bounds__(256) void scanC(
    const int* __restrict__ deg, const int* __restrict__ partial,
    int* __restrict__ row_start, int* __restrict__ cursor, int N)
{
    __shared__ int ssum[256];
    const int base = blockIdx.x * SCAN_BLK;
    int loc[8];
    int s = 0;
#pragma unroll
    for (int j = 0; j < 8; ++j) {
        const int idx = base + threadIdx.x * 8 + j;
        loc[j] = (idx < N) ? deg[idx] : 0;
        s += loc[j];
    }
    ssum[threadIdx.x] = s;
    __syncthreads();
    // inclusive Hillis-Steele scan over 256 thread sums
    for (int off = 1; off < 256; off <<= 1) {
        const int mine = ssum[threadIdx.x];
        const int add  = (threadIdx.x >= (unsigned)off) ? ssum[threadIdx.x - off] : 0;
        __syncthreads();
        ssum[threadIdx.x] = mine + add;
        __syncthreads();
    }
    int run = partial[blockIdx.x] + ssum[threadIdx.x] - s;  // exclusive offset
#pragma unroll
    for (int j = 0; j < 8; ++j) {
        const int idx = base + threadIdx.x * 8 + j;
        if (idx < N) { row_start[idx] = run; cursor[idx] = run; run += loc[j]; }
    }
}

__global__ __launch_bounds__(256) void fill_kernel(
    const int* __restrict__ src, const int* __restrict__ dst,
    int* __restrict__ cursor, int2* __restrict__ csr, int E)
{
    int i = blockIdx.x * blockDim.x + threadIdx.x;
    const int stride = gridDim.x * blockDim.x;
    for (; i < E; i += stride) {
        const int d = dst[i];
        const int pos = atomicAdd(&cursor[d], 1);
        csr[pos] = make_int2(src[i], i);
    }
}

// One wave per node; 4-way unrolled edge loop -> 12 loads in flight per wave
// (round-11 post-mortem: serial dep chain left gather latency-bound at 19% BW).
__global__ __launch_bounds__(256) void gather_kernel(
    const float* __restrict__ feat, const float* __restrict__ ef,
    const int2* __restrict__ csr, const int* __restrict__ row_start,
    const int* __restrict__ deg,
    float* __restrict__ mean_src /* = d_out */, float* __restrict__ mean_edge,
    int N)
{
    const int v = blockIdx.x * 4 + (threadIdx.x >> 6);
    const int lane = threadIdx.x & 63;
    if (v >= N) return;
    const int start = row_start[v];
    const int dv    = deg[v];
    const int2* __restrict__ row = csr + start;
    const int l2 = lane * 2;

    float2 a0 = {0.f,0.f}, a1 = {0.f,0.f}, a2 = {0.f,0.f}, a3 = {0.f,0.f};
    float  e0 = 0.f, e1 = 0.f, e2 = 0.f, e3 = 0.f;

    int i = 0;
    for (; i + 4 <= dv; i += 4) {
        const int2 p0 = row[i + 0];
        const int2 p1 = row[i + 1];
        const int2 p2 = row[i + 2];
        const int2 p3 = row[i + 3];
        const float2 f0 = *reinterpret_cast<const float2*>(feat + (size_t)p0.x * IN_F + l2);
        const float2 f1 = *reinterpret_cast<const float2*>(feat + (size_t)p1.x * IN_F + l2);
        const float2 f2 = *reinterpret_cast<const float2*>(feat + (size_t)p2.x * IN_F + l2);
        const float2 f3 = *reinterpret_cast<const float2*>(feat + (size_t)p3.x * IN_F + l2);
        a0.x += f0.x; a0.y += f0.y;
        a1.x += f1.x; a1.y += f1.y;
        a2.x += f2.x; a2.y += f2.y;
        a3.x += f3.x; a3.y += f3.y;
        if (lane < EF) {
            e0 += ef[(size_t)p0.y * EF + lane];
            e1 += ef[(size_t)p1.y * EF + lane];
            e2 += ef[(size_t)p2.y * EF + lane];
            e3 += ef[(size_t)p3.y * EF + lane];
        }
    }
    for (; i < dv; ++i) {
        const int2 p = row[i];
        const float2 f = *reinterpret_cast<const float2*>(feat + (size_t)p.x * IN_F + l2);
        a0.x += f.x; a0.y += f.y;
        if (lane < EF) e0 += ef[(size_t)p.y * EF + lane];
    }

    const float s = 1.0f / fmaxf((float)dv, 1.0f);
    float2 r;
    r.x = ((a0.x + a1.x) + (a2.x + a3.x)) * s;
    r.y = ((a0.y + a1.y) + (a2.y + a3.y)) * s;
    *reinterpret_cast<float2*>(mean_src + (size_t)v * IN_F + l2) = r;
    if (lane < EF) mean_edge[(size_t)v * EF + lane] = ((e0 + e1) + (e2 + e3)) * s;
}

// ===========================================================================
// Fallback-path kernel (proven round-9 atomic scatter), used if ws too small
// ===========================================================================
__global__ __launch_bounds__(256) void edge_agg(
    const float* __restrict__ feat, const float* __restrict__ ef,
    const int* __restrict__ src, const int* __restrict__ dst,
    float* sum_src /* = d_out */, float* __restrict__ sum_edge,
    float* __restrict__ deg, int E)
{
    const int gid  = blockIdx.x * blockDim.x + threadIdx.x;
    const int wave = gid >> 6;
    const int lane = threadIdx.x & 63;
    const int sub  = lane >> 5;
    const int l    = lane & 31;
    const int nw   = (gridDim.x * blockDim.x) >> 6;

    for (int e2 = wave * 2; e2 < E; e2 += nw * 2) {
        const int e = e2 + sub;
        if (e < E) {
            const int s = src[e];
            const int d = dst[e];
            const float4 v = *reinterpret_cast<const float4*>(
                feat + (size_t)s * IN_F + l * 4);
            float* row = sum_src + (size_t)d * IN_F + l * 4;
            unsafeAtomicAdd(row + 0, v.x);
            unsafeAtomicAdd(row + 1, v.y);
            unsafeAtomicAdd(row + 2, v.z);
            unsafeAtomicAdd(row + 3, v.w);
            const float ev = ef[(size_t)e * EF + l];
            unsafeAtomicAdd(sum_edge + (size_t)d * EF + l, ev);
            if (l == 0) unsafeAtomicAdd(deg + d, 1.0f);
        }
    }
}

// ===========================================================================
// Node GEMM, 64-node tile: out = [feat ; nsrc*inv ; nedge*inv] @ W + bias
// (round-11: 32-node tile re-staged W 460 MB; 64-node tile halves that.)
// Thread (trow=t>>5, tcol=t&31): nodes trow*8..+7, outputs tcol*4..+3.
// sum_src aliases out: own-block rows read before final barrier, written after.
// ===========================================================================
__global__ __launch_bounds__(256) void node_gemm(
    const float* __restrict__ feat, const float* sum_src,
    const float* __restrict__ sum_edge, const float* __restrict__ deg,
    const float* __restrict__ W_self, const float* __restrict__ W_neigh,
    const float* __restrict__ bias, float* out, int N, int need_inv)
{
    __shared__ float xs[64][32];    // [node][k]
    __shared__ float ws[32][128];   // [k][out]
    __shared__ float inv[64];
    __shared__ float bs[128];

    const int t    = threadIdx.x;
    const int tcol = t & 31;
    const int trow = t >> 5;        // 0..7
    const int base = blockIdx.x * 64;

    if (t < 128) bs[t] = bias[t];
    if (t < 64) {
        float iv = 1.0f;
        if (need_inv) {
            const int nv = base + t;
            const float d = (nv < N) ? deg[nv] : 1.0f;
            iv = 1.0f / fmaxf(d, 1.0f);
        }
        inv[t] = iv;
    }
    __syncthreads();

    float acc[8][4];
#pragma unroll
    for (int i = 0; i < 8; ++i)
#pragma unroll
        for (int j = 0; j < 4; ++j) acc[i][j] = 0.0f;

#pragma unroll 1
    for (int kc = 0; kc < 9; ++kc) {
        const int k0 = kc * 32;

        // ---- stage x tile (64 nodes x 32 k): 2 float4 per thread ----
#pragma unroll
        for (int p = 0; p < 2; ++p) {
            const int fid = t * 2 + p;      // 0..511
            const int sn  = fid >> 3;       // node 0..63
            const int kq  = (fid & 7) * 4;  // k 0,4,..,28
            const int nv  = base + sn;
            float4 v = make_float4(0.f, 0.f, 0.f, 0.f);
            if (nv < N) {
                if (kc < 4) {
                    v = *reinterpret_cast<const float4*>(
                        feat + (size_t)nv * IN_F + k0 + kq);
                } else if (kc < 8) {
                    v = *reinterpret_cast<const float4*>(
                        sum_src + (size_t)nv * IN_F + (k0 - 128) + kq);
                    const float sc = inv[sn];
                    v.x *= sc; v.y *= sc; v.z *= sc; v.w *= sc;
                } else {
                    v = *reinterpret_cast<const float4*>(
                        sum_edge + (size_t)nv * EF + kq);
                    const float sc = inv[sn];
                    v.x *= sc; v.y *= sc; v.z *= sc; v.w *= sc;
                }
            }
            *reinterpret_cast<float4*>(&xs[sn][kq]) = v;
        }

        // ---- stage W tile (32 k x 128 out): 4 float4 per thread ----
#pragma unroll
        for (int p = 0; p < 4; ++p) {
            const int ei  = p * 1024 + t * 4;
            const int row = ei >> 7;
            const int col = ei & 127;
            float4 w4;
            if (kc < 4) {
                w4 = *reinterpret_cast<const float4*>(
                    W_self + (size_t)(k0 + row) * OUT_F + col);
            } else {
                w4 = *reinterpret_cast<const float4*>(
                    W_neigh + (size_t)(k0 - 128 + row) * OUT_F + col);
            }
            *reinterpret_cast<float4*>(&ws[row][col]) = w4;
        }
        __syncthreads();

        // ---- compute ----
#pragma unroll
        for (int kk = 0; kk < 32; ++kk) {
            const float4 b = *reinterpret_cast<const float4*>(&ws[kk][tcol * 4]);
#pragma unroll
            for (int i = 0; i < 8; ++i) {
                const float a = xs[trow * 8 + i][kk];
                acc[i][0] = fmaf(a, b.x, acc[i][0]);
                acc[i][1] = fmaf(a, b.y, acc[i][1]);
                acc[i][2] = fmaf(a, b.z, acc[i][2]);
                acc[i][3] = fmaf(a, b.w, acc[i][3]);
            }
        }
        __syncthreads();
    }

    // ---- epilogue (after final barrier: all aliased reads are done) ----
#pragma unroll
    for (int i = 0; i < 8; ++i) {
        const int nv = base + trow * 8 + i;
        if (nv < N) {
            float4 r;
            r.x = acc[i][0] + bs[tcol * 4 + 0];
            r.y = acc[i][1] + bs[tcol * 4 + 1];
            r.z = acc[i][2] + bs[tcol * 4 + 2];
            r.w = acc[i][3] + bs[tcol * 4 + 3];
            *reinterpret_cast<float4*>(out + (size_t)nv * OUT_F + tcol * 4) = r;
        }
    }
}

extern "C" void kernel_launch(void* const* d_in, const int* in_sizes, int n_in,
                              void* d_out, int out_size, void* d_ws, size_t ws_size,
                              hipStream_t stream) {
    const float* feat    = (const float*)d_in[0];
    const float* efeats  = (const float*)d_in[1];
    const int*   src     = (const int*)d_in[2];
    const int*   dst     = (const int*)d_in[3];
    const float* W_self  = (const float*)d_in[4];
    const float* W_neigh = (const float*)d_in[5];
    const float* bias    = (const float*)d_in[6];
    float* out = (float*)d_out;

    const int N = in_sizes[0] / IN_F;   // 100000
    const int E = in_sizes[2];          // 1600000
    const int nblk_gemm = (N + 63) / 64;

    // ---- CSR-path workspace layout ----
    char* p = (char*)d_ws;
    float* mean_edge = (float*)p;                 p += (size_t)N * EF * sizeof(float);
    int2*  csr       = (int2*)p;                  p += (size_t)E * sizeof(int2);
    int*   deg_i     = (int*)p;                   p += (size_t)N * sizeof(int);
    int*   row_start = (int*)p;                   p += (size_t)N * sizeof(int);
    int*   cursor    = (int*)p;                   p += (size_t)N * sizeof(int);
    int*   partial   = (int*)p;                   p += 64 * sizeof(int);
    const size_t need_csr = (size_t)(p - (char*)d_ws);

    if (ws_size >= need_csr) {
        // ======== CSR path: build bins, then atomic-free gather ========
        const int NB = (N + SCAN_BLK - 1) / SCAN_BLK;   // 49 <= 64
        hipMemsetAsync(deg_i, 0, (size_t)N * sizeof(int), stream);
        hist_kernel<<<1024, 256, 0, stream>>>(dst, deg_i, E);
        scanA<<<NB, 256, 0, stream>>>(deg_i, partial, N);
        scanB<<<1, 64, 0, stream>>>(partial, NB);
        scanC<<<NB, 256, 0, stream>>>(deg_i, partial, row_start, cursor, N);
        fill_kernel<<<1024, 256, 0, stream>>>(src, dst, cursor, csr, E);
        gather_kernel<<<(N + 3) / 4, 256, 0, stream>>>(
            feat, efeats, csr, row_start, deg_i, out, mean_edge, N);
        node_gemm<<<nblk_gemm, 256, 0, stream>>>(
            feat, out, mean_edge, (const float*)deg_i /*unused*/,
            W_self, W_neigh, bias, out, N, /*need_inv=*/0);
    } else {
        // ======== Fallback: proven round-9 atomic-scatter path ========
        float* sum_edge = (float*)d_ws;
        float* deg_f    = sum_edge + (size_t)N * EF;
        const size_t ws_bytes = ((size_t)N * EF + N) * sizeof(float);
        hipMemsetAsync(d_out, 0, (size_t)N * IN_F * sizeof(float), stream);
        hipMemsetAsync(d_ws, 0, ws_bytes, stream);
        edge_agg<<<4096, 256, 0, stream>>>(feat, efeats, src, dst,
                                           out, sum_edge, deg_f, E);
        node_gemm<<<nblk_gemm, 256, 0, stream>>>(
            feat, out, sum_edge, deg_f,
            W_self, W_neigh, bias, out, N, /*need_inv=*/1);
    }
}